// Round 11
// baseline (1434.217 us; speedup 1.0000x reference)
//
#include <hip/hip_runtime.h>
#include <hip/hip_bf16.h>

#define DIM 128
#define EPB 8192          // edges per partition chunk (1024 thr x 8)
#define SRC_BITS 17       // n_nodes < 131072
#define SRC_MASK 0x1FFFF
#define BKT 128           // nodes per bucket (dst>>7), 64KB LDS accumulator

typedef short short8 __attribute__((ext_vector_type(8)));
typedef float f32x4 __attribute__((ext_vector_type(4)));

static __device__ __forceinline__ unsigned short f2bf(float f) {
    unsigned u = __builtin_bit_cast(unsigned, f);
    unsigned r = (u + 0x7fffu + ((u >> 16) & 1u)) >> 16;  // RNE
    return (unsigned short)r;
}

// -------------------- GEMM: S2 = bf16(X @ W) via MFMA --------------------
// Split-column layout: uint word j of row holds bf16 pair (col j, col j+64),
// so the reduce's lane l handles cols (l, l+64) with 4B-stride LDS accum.
__global__ __launch_bounds__(256) void gemm_xw_mfma(const float* __restrict__ X,
                                                    const float* __restrict__ W,
                                                    unsigned short* __restrict__ S2,
                                                    int n_nodes) {
    __shared__ unsigned short wlds[DIM * DIM];  // 32 KB, swizzled W^T bf16

    for (int idx = threadIdx.x; idx < DIM * DIM; idx += 256) {
        const int k = idx >> 7;
        const int n = idx & 127;
        wlds[n * DIM + (k ^ ((n & 7) << 3))] = f2bf(W[idx]);
    }
    __syncthreads();

    const int wave = threadIdx.x >> 6;
    const int lane = threadIdx.x & 63;
    const int row_base = blockIdx.x * 64 + wave * 16;
    const int mrow = lane & 15;
    const int kq = lane >> 4;
    const int kq8 = kq * 8;

    int rr = row_base + mrow;
    if (rr >= n_nodes) rr = n_nodes - 1;
    const float4* Xr = (const float4*)(X + (size_t)rr * DIM);

    short8 a[4];
#pragma unroll
    for (int s = 0; s < 4; ++s) {
        const float4 v0 = Xr[s * 8 + kq * 2];
        const float4 v1 = Xr[s * 8 + kq * 2 + 1];
        short8 av;
        av[0] = f2bf(v0.x); av[1] = f2bf(v0.y); av[2] = f2bf(v0.z); av[3] = f2bf(v0.w);
        av[4] = f2bf(v1.x); av[5] = f2bf(v1.y); av[6] = f2bf(v1.z); av[7] = f2bf(v1.w);
        a[s] = av;
    }

    f32x4 acc[8];
#pragma unroll
    for (int c = 0; c < 8; ++c) acc[c] = (f32x4){0.f, 0.f, 0.f, 0.f};

    const int swz = (lane & 7) << 3;
#pragma unroll
    for (int s = 0; s < 4; ++s) {
        const int k0 = s * 32 + kq8;
#pragma unroll
        for (int c = 0; c < 8; ++c) {
            const int n = c * 16 + mrow;
            const short8 bv = *(const short8*)(&wlds[n * DIM + (k0 ^ swz)]);
            acc[c] = __builtin_amdgcn_mfma_f32_16x16x32_bf16(a[s], bv, acc[c], 0, 0, 0);
        }
    }

#pragma unroll
    for (int reg = 0; reg < 4; ++reg) {
        const int g_r = row_base + kq * 4 + reg;
        if (g_r < n_nodes) {
            unsigned short* orow = S2 + (size_t)g_r * DIM;
#pragma unroll
            for (int c = 0; c < 8; ++c) {
                const int n = c * 16 + mrow;
                orow[(n & 63) * 2 + (n >> 6)] = f2bf(acc[c][reg]);
            }
        }
    }
}

// ---------- Pass A: per-chunk LDS histogram of buckets (bucket = dst>>7) ----------
// cnt[b * nchunks + blk] fully overwritten -> no zeroing kernel needed.
__global__ __launch_bounds__(1024) void partA_hist(const int* __restrict__ dst,
                                                   int* __restrict__ cnt,
                                                   int n_edges, int nchunks, int nbkt) {
    __shared__ int lc[1024];
    const int blk = blockIdx.x;
    lc[threadIdx.x] = 0;
    __syncthreads();
    const int base = blk * EPB;
#pragma unroll
    for (int u = 0; u < 8; ++u) {
        const int e = base + u * 1024 + threadIdx.x;
        if (e < n_edges) atomicAdd(&lc[dst[e] >> 7], 1);
    }
    __syncthreads();
    for (int b = threadIdx.x; b < nbkt; b += 1024) cnt[b * nchunks + blk] = lc[b];
}

// ---------- scan of the (nbkt x nchunks) count matrix, bucket-major ----------
#define SCAN_B 1024
__global__ __launch_bounds__(SCAN_B) void scan_block(const int* __restrict__ in,
                                                     int* __restrict__ outv,
                                                     int* __restrict__ bsum,
                                                     int n) {
    __shared__ int lds[SCAN_B];
    const int i = blockIdx.x * SCAN_B + threadIdx.x;
    int v = (i < n) ? in[i] : 0;
    const int own = v;
    lds[threadIdx.x] = v;
    __syncthreads();
#pragma unroll
    for (int off = 1; off < SCAN_B; off <<= 1) {
        int t = (threadIdx.x >= off) ? lds[threadIdx.x - off] : 0;
        __syncthreads();
        lds[threadIdx.x] += t;
        __syncthreads();
    }
    if (i < n) outv[i] = lds[threadIdx.x] - own;  // exclusive
    if (threadIdx.x == SCAN_B - 1) bsum[blockIdx.x] = lds[threadIdx.x];
}

__global__ __launch_bounds__(SCAN_B) void scan_tops(int* __restrict__ bsum, int nblocks) {
    __shared__ int lds[SCAN_B];
    int v = (threadIdx.x < nblocks) ? bsum[threadIdx.x] : 0;
    const int own = v;
    lds[threadIdx.x] = v;
    __syncthreads();
#pragma unroll
    for (int off = 1; off < SCAN_B; off <<= 1) {
        int t = (threadIdx.x >= off) ? lds[threadIdx.x - off] : 0;
        __syncthreads();
        lds[threadIdx.x] += t;
        __syncthreads();
    }
    if (threadIdx.x < nblocks) bsum[threadIdx.x] = lds[threadIdx.x] - own;
}

__global__ __launch_bounds__(SCAN_B) void scan_fix(int* __restrict__ outv,
                                                   const int* __restrict__ bsum,
                                                   int n) {
    const int i = blockIdx.x * SCAN_B + threadIdx.x;
    if (i < n) outv[i] += bsum[blockIdx.x];
}

// ---------- Pass B: scatter packed records into bucket order (LDS ranks only) ------
__global__ __launch_bounds__(1024) void partB_scatter(const int* __restrict__ dst,
                                                      const int* __restrict__ src,
                                                      const float* __restrict__ ew,
                                                      const int* __restrict__ cb,
                                                      int2* __restrict__ part_sw,
                                                      int n_edges, int nchunks) {
    __shared__ int lc[1024];
    const int blk = blockIdx.x;
    lc[threadIdx.x] = 0;
    __syncthreads();
    const int base = blk * EPB;
#pragma unroll
    for (int u = 0; u < 8; ++u) {
        const int e = base + u * 1024 + threadIdx.x;
        if (e < n_edges) {
            const int d = dst[e];
            const int bin = d >> 7;
            const int r = atomicAdd(&lc[bin], 1);
            const int pos = cb[bin * nchunks + blk] + r;
            part_sw[pos] = make_int2(src[e] | ((d & (BKT - 1)) << SRC_BITS),
                                     __float_as_int(ew[e]));
        }
    }
}

// ---------- fused reduce: per-bucket LDS accumulation, bias, coalesced out ----------
// Block = 512 thr (8 waves), one 128-node bucket, 64KB fp32 accumulator.
// Edge: 64-lane gather of S2 row (word l = cols l, l+64) + 2 free ds_add_f32.
__global__ __launch_bounds__(512) void bucket_reduce(const unsigned int* __restrict__ S2w,
                                                     const int2* __restrict__ part_sw,
                                                     const int* __restrict__ cb,
                                                     const float* __restrict__ bias,
                                                     float* __restrict__ out,
                                                     int n_nodes, int n_edges,
                                                     int nchunks, int nbkt) {
    __shared__ float accum[BKT * DIM];  // 64 KB
    const int b = blockIdx.x;
    const int bstart = cb[b * nchunks];
    const int bend = (b + 1 < nbkt) ? cb[(b + 1) * nchunks] : n_edges;

    float4* a4 = (float4*)accum;
#pragma unroll
    for (int i = 0; i < 8; ++i)
        a4[i * 512 + threadIdx.x] = make_float4(0.f, 0.f, 0.f, 0.f);
    __syncthreads();

    const int wave = threadIdx.x >> 6;
    const int lane = threadIdx.x & 63;

    for (int sbase = bstart + wave * 64; sbase < bend; sbase += 512) {
        const int cnt = min(64, bend - sbase);
        int2 meta = make_int2(0, 0);
        if (lane < cnt) meta = part_sw[sbase + lane];

        int i = 0;
        for (; i + 8 <= cnt; i += 8) {
            unsigned int gv[8];
            int mxs[8];
#pragma unroll
            for (int u = 0; u < 8; ++u) {
                mxs[u] = __shfl(meta.x, i + u, 64);
                gv[u] = S2w[(size_t)(mxs[u] & SRC_MASK) * 64 + lane];
            }
#pragma unroll
            for (int u = 0; u < 8; ++u) {
                const float w = __int_as_float(__shfl(meta.y, i + u, 64));
                const int dlow = (mxs[u] >> SRC_BITS) & (BKT - 1);
                const float fx = __int_as_float(gv[u] << 16);
                const float fy = __int_as_float(gv[u] & 0xffff0000u);
                atomicAdd(&accum[dlow * DIM + lane], w * fx);
                atomicAdd(&accum[dlow * DIM + 64 + lane], w * fy);
            }
        }
        for (; i < cnt; ++i) {
            const int mx = __shfl(meta.x, i, 64);
            const float w = __int_as_float(__shfl(meta.y, i, 64));
            const unsigned int g = S2w[(size_t)(mx & SRC_MASK) * 64 + lane];
            const int dlow = (mx >> SRC_BITS) & (BKT - 1);
            atomicAdd(&accum[dlow * DIM + lane], w * __int_as_float(g << 16));
            atomicAdd(&accum[dlow * DIM + 64 + lane],
                      w * __int_as_float(g & 0xffff0000u));
        }
    }
    __syncthreads();

    const int nb0 = b << 7;
    const float4* b4 = (const float4*)bias;
#pragma unroll
    for (int t = 0; t < 8; ++t) {
        const int flat4 = t * 512 + threadIdx.x;
        const int node = nb0 + (flat4 >> 5);
        if (node < n_nodes) {
            const float4 v = a4[flat4];
            const float4 bb = b4[flat4 & 31];
            float4 o = {v.x + bb.x, v.y + bb.y, v.z + bb.z, v.w + bb.w};
            ((float4*)out)[(size_t)nb0 * 32 + flat4] = o;
        }
    }
}

extern "C" void kernel_launch(void* const* d_in, const int* in_sizes, int n_in,
                              void* d_out, int out_size, void* d_ws, size_t ws_size,
                              hipStream_t stream) {
    const float* X    = (const float*)d_in[0];
    const float* W    = (const float*)d_in[1];
    const float* bias = (const float*)d_in[2];
    const float* ew   = (const float*)d_in[3];
    const int*   src  = (const int*)d_in[4];
    const int*   dst  = (const int*)d_in[5];
    float* out = (float*)d_out;

    const int n_nodes = in_sizes[0] / DIM;
    const int n_edges = in_sizes[3];

    const int nbkt = (n_nodes + BKT - 1) >> 7;             // 782
    const int nchunks = (n_edges + EPB - 1) / EPB;         // 196
    const int N2 = nbkt * nchunks;                         // ~153K

    // Workspace layout (bytes):
    char* ws = (char*)d_ws;
    unsigned short* S2 = (unsigned short*)ws;                         // 25.6 MB
    char* p = ws + (size_t)n_nodes * DIM * 2;
    int* cnt = (int*)p;             p += (size_t)N2 * 4;              // ~613 KB
    int* cb  = (int*)p;             p += (size_t)N2 * 4;              // ~613 KB
    int* bsum = (int*)p;            p += SCAN_B * 4;                  // 4 KB
    int2* part_sw = (int2*)p;                                         // 12.8 MB

    // 1. GEMM (bf16 MFMA, fp32 accumulate, split-column bf16 store)
    gemm_xw_mfma<<<(n_nodes + 63) / 64, 256, 0, stream>>>(X, W, S2, n_nodes);

    // 2. Bucket partition (all atomics LDS-scope)
    partA_hist<<<nchunks, 1024, 0, stream>>>(dst, cnt, n_edges, nchunks, nbkt);

    const int nblocks = (N2 + SCAN_B - 1) / SCAN_B;
    scan_block<<<nblocks, SCAN_B, 0, stream>>>(cnt, cb, bsum, N2);
    scan_tops<<<1, SCAN_B, 0, stream>>>(bsum, nblocks);
    scan_fix<<<nblocks, SCAN_B, 0, stream>>>(cb, bsum, N2);

    partB_scatter<<<nchunks, 1024, 0, stream>>>(dst, src, ew, cb, part_sw,
                                                n_edges, nchunks);

    // 3. Fused per-bucket reduction (LDS accum, bias fused, coalesced out)
    bucket_reduce<<<nbkt, 512, 0, stream>>>((const unsigned int*)S2, part_sw, cb,
                                            bias, out, n_nodes, n_edges,
                                            nchunks, nbkt);
}

// Round 12
// 156.032 us; speedup vs baseline: 9.1918x; 9.1918x over previous
//
#include <hip/hip_runtime.h>
#include <hip/hip_bf16.h>

#define DIM 128
#define EPB 8192          // edges per partition chunk (1024 thr x 8)
#define SRC_BITS 17       // n_nodes < 131072
#define SRC_MASK 0x1FFFF
#define BKT 128           // nodes per bucket (dst>>7)
#define RCAP 4096         // record capacity per tile (mean 2048, sd ~45)

typedef short short8 __attribute__((ext_vector_type(8)));
typedef float f32x4 __attribute__((ext_vector_type(4)));

static __device__ __forceinline__ unsigned short f2bf(float f) {
    unsigned u = __builtin_bit_cast(unsigned, f);
    unsigned r = (u + 0x7fffu + ((u >> 16) & 1u)) >> 16;  // RNE
    return (unsigned short)r;
}

// -------------------- GEMM: S2 = bf16(X @ W) via MFMA (plain row layout) ----------
__global__ __launch_bounds__(256) void gemm_xw_mfma(const float* __restrict__ X,
                                                    const float* __restrict__ W,
                                                    unsigned short* __restrict__ S2,
                                                    int n_nodes) {
    __shared__ unsigned short wlds[DIM * DIM];  // 32 KB, swizzled W^T bf16

    for (int idx = threadIdx.x; idx < DIM * DIM; idx += 256) {
        const int k = idx >> 7;
        const int n = idx & 127;
        wlds[n * DIM + (k ^ ((n & 7) << 3))] = f2bf(W[idx]);
    }
    __syncthreads();

    const int wave = threadIdx.x >> 6;
    const int lane = threadIdx.x & 63;
    const int row_base = blockIdx.x * 64 + wave * 16;
    const int mrow = lane & 15;
    const int kq = lane >> 4;
    const int kq8 = kq * 8;

    int rr = row_base + mrow;
    if (rr >= n_nodes) rr = n_nodes - 1;
    const float4* Xr = (const float4*)(X + (size_t)rr * DIM);

    short8 a[4];
#pragma unroll
    for (int s = 0; s < 4; ++s) {
        const float4 v0 = Xr[s * 8 + kq * 2];
        const float4 v1 = Xr[s * 8 + kq * 2 + 1];
        short8 av;
        av[0] = f2bf(v0.x); av[1] = f2bf(v0.y); av[2] = f2bf(v0.z); av[3] = f2bf(v0.w);
        av[4] = f2bf(v1.x); av[5] = f2bf(v1.y); av[6] = f2bf(v1.z); av[7] = f2bf(v1.w);
        a[s] = av;
    }

    f32x4 acc[8];
#pragma unroll
    for (int c = 0; c < 8; ++c) acc[c] = (f32x4){0.f, 0.f, 0.f, 0.f};

    const int swz = (lane & 7) << 3;
#pragma unroll
    for (int s = 0; s < 4; ++s) {
        const int k0 = s * 32 + kq8;
#pragma unroll
        for (int c = 0; c < 8; ++c) {
            const int n = c * 16 + mrow;
            const short8 bv = *(const short8*)(&wlds[n * DIM + (k0 ^ swz)]);
            acc[c] = __builtin_amdgcn_mfma_f32_16x16x32_bf16(a[s], bv, acc[c], 0, 0, 0);
        }
    }

#pragma unroll
    for (int reg = 0; reg < 4; ++reg) {
        const int g_r = row_base + kq * 4 + reg;
        if (g_r < n_nodes) {
            unsigned short* orow = S2 + (size_t)g_r * DIM + mrow;
#pragma unroll
            for (int c = 0; c < 8; ++c) orow[c * 16] = f2bf(acc[c][reg]);
        }
    }
}

// ---------- Pass A: per-chunk LDS histogram of buckets (bucket = dst>>7) ----------
__global__ __launch_bounds__(1024) void partA_hist(const int* __restrict__ dst,
                                                   int* __restrict__ cnt,
                                                   int n_edges, int nchunks, int nbkt) {
    __shared__ int lc[1024];
    const int blk = blockIdx.x;
    lc[threadIdx.x] = 0;
    __syncthreads();
    const int base = blk * EPB;
#pragma unroll
    for (int u = 0; u < 8; ++u) {
        const int e = base + u * 1024 + threadIdx.x;
        if (e < n_edges) atomicAdd(&lc[dst[e] >> 7], 1);
    }
    __syncthreads();
    for (int b = threadIdx.x; b < nbkt; b += 1024) cnt[b * nchunks + blk] = lc[b];
}

// ---------- scan of the (nbkt x nchunks) count matrix, bucket-major ----------
#define SCAN_B 1024
__global__ __launch_bounds__(SCAN_B) void scan_block(const int* __restrict__ in,
                                                     int* __restrict__ outv,
                                                     int* __restrict__ bsum,
                                                     int n) {
    __shared__ int lds[SCAN_B];
    const int i = blockIdx.x * SCAN_B + threadIdx.x;
    int v = (i < n) ? in[i] : 0;
    const int own = v;
    lds[threadIdx.x] = v;
    __syncthreads();
#pragma unroll
    for (int off = 1; off < SCAN_B; off <<= 1) {
        int t = (threadIdx.x >= off) ? lds[threadIdx.x - off] : 0;
        __syncthreads();
        lds[threadIdx.x] += t;
        __syncthreads();
    }
    if (i < n) outv[i] = lds[threadIdx.x] - own;  // exclusive
    if (threadIdx.x == SCAN_B - 1) bsum[blockIdx.x] = lds[threadIdx.x];
}

__global__ __launch_bounds__(SCAN_B) void scan_tops(int* __restrict__ bsum, int nblocks) {
    __shared__ int lds[SCAN_B];
    int v = (threadIdx.x < nblocks) ? bsum[threadIdx.x] : 0;
    const int own = v;
    lds[threadIdx.x] = v;
    __syncthreads();
#pragma unroll
    for (int off = 1; off < SCAN_B; off <<= 1) {
        int t = (threadIdx.x >= off) ? lds[threadIdx.x - off] : 0;
        __syncthreads();
        lds[threadIdx.x] += t;
        __syncthreads();
    }
    if (threadIdx.x < nblocks) bsum[threadIdx.x] = lds[threadIdx.x] - own;
}

__global__ __launch_bounds__(SCAN_B) void scan_fix(int* __restrict__ outv,
                                                   const int* __restrict__ bsum,
                                                   int n) {
    const int i = blockIdx.x * SCAN_B + threadIdx.x;
    if (i < n) outv[i] += bsum[blockIdx.x];
}

// ---------- Pass B: scatter packed records into bucket order (LDS ranks only) ------
__global__ __launch_bounds__(1024) void partB_scatter(const int* __restrict__ dst,
                                                      const int* __restrict__ src,
                                                      const float* __restrict__ ew,
                                                      const int* __restrict__ cb,
                                                      int2* __restrict__ part_sw,
                                                      int n_edges, int nchunks) {
    __shared__ int lc[1024];
    const int blk = blockIdx.x;
    lc[threadIdx.x] = 0;
    __syncthreads();
    const int base = blk * EPB;
#pragma unroll
    for (int u = 0; u < 8; ++u) {
        const int e = base + u * 1024 + threadIdx.x;
        if (e < n_edges) {
            const int d = dst[e];
            const int bin = d >> 7;
            const int r = atomicAdd(&lc[bin], 1);
            const int pos = cb[bin * nchunks + blk] + r;
            part_sw[pos] = make_int2(src[e] | ((d & (BKT - 1)) << SRC_BITS),
                                     __float_as_int(ew[e]));
        }
    }
}

// ---------- fused CSR-sort + reduce: one 128-node bucket per block --------------
// Phase a: bucket records -> registers, LDS rank (128 counters), LDS scan,
//          scatter RECORDS sorted-by-node into 32KB LDS.
// Phase b: wave w owns nodes w+8j (j=0..15, unrolled -> acc[16] in VGPRs),
//          per-node register reduction with 8-deep gather ILP (meta = uniform
//          LDS reads). Phase c: coalesced float2 out-write with fused bias.
__global__ __launch_bounds__(512) void bucket_csr_reduce(
        const unsigned int* __restrict__ S2w,
        const int2* __restrict__ part_sw,
        const int* __restrict__ cb,
        const float* __restrict__ bias,
        float* __restrict__ out,
        int n_nodes, int n_edges, int nchunks, int nbkt) {
    __shared__ int2 recs[RCAP];   // 32 KB sorted records
    __shared__ int lcnt[BKT];
    __shared__ int loff[BKT];

    const int b = blockIdx.x;
    const int bstart = cb[b * nchunks];
    const int bend = (b + 1 < nbkt) ? cb[(b + 1) * nchunks] : n_edges;
    const int wave = threadIdx.x >> 6;
    const int lane = threadIdx.x & 63;
    const int nb0 = b << 7;

    float2 acc[16];
#pragma unroll
    for (int j = 0; j < 16; ++j) acc[j] = make_float2(0.f, 0.f);

    for (int tstart = bstart; tstart < bend; tstart += RCAP) {
        const int tcnt = min(RCAP, bend - tstart);

        if (threadIdx.x < BKT) lcnt[threadIdx.x] = 0;
        __syncthreads();

        // load to registers + rank
        int2 myrec[8];
        int myrank[8];
#pragma unroll
        for (int u = 0; u < 8; ++u) {
            const int i = threadIdx.x + u * 512;
            if (i < tcnt) {
                myrec[u] = part_sw[tstart + i];
                myrank[u] = atomicAdd(&lcnt[(myrec[u].x >> SRC_BITS) & (BKT - 1)], 1);
            }
        }
        __syncthreads();

        // exclusive scan of lcnt -> loff (128 entries, block-uniform barriers)
        if (threadIdx.x < BKT) loff[threadIdx.x] = lcnt[threadIdx.x];
        __syncthreads();
#pragma unroll
        for (int off = 1; off < BKT; off <<= 1) {
            int t_ = 0;
            if (threadIdx.x < BKT && threadIdx.x >= off) t_ = loff[threadIdx.x - off];
            __syncthreads();
            if (threadIdx.x < BKT) loff[threadIdx.x] += t_;
            __syncthreads();
        }
        int ex = 0;
        if (threadIdx.x < BKT && threadIdx.x > 0) ex = loff[threadIdx.x - 1];
        __syncthreads();
        if (threadIdx.x < BKT) loff[threadIdx.x] = ex;
        __syncthreads();

        // scatter records into sorted position
#pragma unroll
        for (int u = 0; u < 8; ++u) {
            const int i = threadIdx.x + u * 512;
            if (i < tcnt) {
                const int dlow = (myrec[u].x >> SRC_BITS) & (BKT - 1);
                recs[loff[dlow] + myrank[u]] = myrec[u];
            }
        }
        __syncthreads();

        // per-node register reduction; wave w -> nodes w + 8j
#pragma unroll
        for (int j = 0; j < 16; ++j) {
            const int dlow = wave + (j << 3);
            const int s0 = loff[dlow];
            const int s1 = s0 + lcnt[dlow];

            int i = s0;
            for (; i + 8 <= s1; i += 8) {
                unsigned int gv[8];
                float ws[8];
#pragma unroll
                for (int u = 0; u < 8; ++u) {
                    const int2 r = recs[i + u];  // uniform (broadcast) LDS read
                    ws[u] = __int_as_float(r.y);
                    gv[u] = S2w[(size_t)(r.x & SRC_MASK) * 64 + lane];
                }
#pragma unroll
                for (int u = 0; u < 8; ++u) {
                    const float fx = __int_as_float(gv[u] << 16);
                    const float fy = __int_as_float(gv[u] & 0xffff0000u);
                    acc[j].x = fmaf(ws[u], fx, acc[j].x);
                    acc[j].y = fmaf(ws[u], fy, acc[j].y);
                }
            }
            for (; i < s1; ++i) {
                const int2 r = recs[i];
                const float w = __int_as_float(r.y);
                const unsigned int g = S2w[(size_t)(r.x & SRC_MASK) * 64 + lane];
                acc[j].x = fmaf(w, __int_as_float(g << 16), acc[j].x);
                acc[j].y = fmaf(w, __int_as_float(g & 0xffff0000u), acc[j].y);
            }
        }
        __syncthreads();  // recs/lcnt/loff reused next tile
    }

    // epilogue: out = acc + bias, fully coalesced
    const float2 bb = ((const float2*)bias)[lane];
#pragma unroll
    for (int j = 0; j < 16; ++j) {
        const int node = nb0 + wave + (j << 3);
        if (node < n_nodes) {
            float2 o = {acc[j].x + bb.x, acc[j].y + bb.y};
            ((float2*)(out + (size_t)node * DIM))[lane] = o;
        }
    }
}

extern "C" void kernel_launch(void* const* d_in, const int* in_sizes, int n_in,
                              void* d_out, int out_size, void* d_ws, size_t ws_size,
                              hipStream_t stream) {
    const float* X    = (const float*)d_in[0];
    const float* W    = (const float*)d_in[1];
    const float* bias = (const float*)d_in[2];
    const float* ew   = (const float*)d_in[3];
    const int*   src  = (const int*)d_in[4];
    const int*   dst  = (const int*)d_in[5];
    float* out = (float*)d_out;

    const int n_nodes = in_sizes[0] / DIM;
    const int n_edges = in_sizes[3];

    const int nbkt = (n_nodes + BKT - 1) >> 7;             // 782
    const int nchunks = (n_edges + EPB - 1) / EPB;         // 196
    const int N2 = nbkt * nchunks;                         // ~153K

    // Workspace layout (bytes):
    char* ws = (char*)d_ws;
    unsigned short* S2 = (unsigned short*)ws;                         // 25.6 MB
    char* p = ws + (size_t)n_nodes * DIM * 2;
    int* cnt = (int*)p;             p += (size_t)N2 * 4;              // ~613 KB
    int* cb  = (int*)p;             p += (size_t)N2 * 4;              // ~613 KB
    int* bsum = (int*)p;            p += SCAN_B * 4;                  // 4 KB
    int2* part_sw = (int2*)p;                                         // 12.8 MB

    // 1. GEMM (bf16 MFMA, fp32 accumulate, bf16 store)
    gemm_xw_mfma<<<(n_nodes + 63) / 64, 256, 0, stream>>>(X, W, S2, n_nodes);

    // 2. Bucket partition (all atomics LDS-scope)
    partA_hist<<<nchunks, 1024, 0, stream>>>(dst, cnt, n_edges, nchunks, nbkt);

    const int nblocks = (N2 + SCAN_B - 1) / SCAN_B;
    scan_block<<<nblocks, SCAN_B, 0, stream>>>(cnt, cb, bsum, N2);
    scan_tops<<<1, SCAN_B, 0, stream>>>(bsum, nblocks);
    scan_fix<<<nblocks, SCAN_B, 0, stream>>>(cb, bsum, N2);

    partB_scatter<<<nchunks, 1024, 0, stream>>>(dst, src, ew, cb, part_sw,
                                                n_edges, nchunks);

    // 3. Fused sort+reduce (register accumulation, bias fused, coalesced out)
    bucket_csr_reduce<<<nbkt, 512, 0, stream>>>((const unsigned int*)S2, part_sw,
                                                cb, bias, out, n_nodes, n_edges,
                                                nchunks, nbkt);
}